// Round 12
// baseline (286.918 us; speedup 1.0000x reference)
//
#include <hip/hip_runtime.h>

// x: (16, 3, 1024, 1024) f32  ->  out: (16, 4, 512, 512) f32
// gray = 0.114*x[:,0] + 0.587*x[:,1] + 0.299*x[:,2]
// 2x2 Haar: a=g[2i,2j], tb=g[2i,2j+1], c=g[2i+1,2j], d=g[2i+1,2j+1]
// cA=(a+tb+c+d)*.5  cH=(a+tb-c-d)*.5  cV=(a-tb+c-d)*.5  cD=(a-tb-c+d)*.5
//
// Memory-bound: ideal traffic = 192 MiB in + 64 MiB out ~= 268 MB -> ~43 us
// at 6.3 TB/s achievable. All accesses 16B/lane coalesced; no reuse -> no LDS.

#define B_  16
#define H_  1024
#define W_  1024
#define OH_ 512
#define OW_ 512

__global__ __launch_bounds__(256) void haar_gray_kernel(
    const float* __restrict__ x, float* __restrict__ out)
{
    // one thread = 4 output pixels (8 input cols x 2 input rows)
    // total threads = 16 * 512 * 128 = 1,048,576
    const int tid = blockIdx.x * blockDim.x + threadIdx.x;

    const int b   = tid >> 16;              // / (512*128)
    const int rem = tid & ((1 << 16) - 1);
    const int i   = rem >> 7;               // output row
    const int tj  = rem & 127;              // quad index within row
    const int j0  = tj << 2;                // output col (multiple of 4 -> 16B aligned)
    const int w0  = tj << 3;                // input col (multiple of 8 -> 32B aligned)
    const int h0  = i << 1;                 // input row (top of pair)

    const float* bp = x + (size_t)b * 3 * H_ * W_;

    const float wb = 0.114f, wg = 0.587f, wr = 0.299f;

    // 3 channels x {top,bottom} x 2 float4 = 12 x 16B coalesced loads
    const float4* p0t = reinterpret_cast<const float4*>(bp + (size_t)(0 * H_ + h0    ) * W_ + w0);
    const float4* p0b = reinterpret_cast<const float4*>(bp + (size_t)(0 * H_ + h0 + 1) * W_ + w0);
    const float4* p1t = reinterpret_cast<const float4*>(bp + (size_t)(1 * H_ + h0    ) * W_ + w0);
    const float4* p1b = reinterpret_cast<const float4*>(bp + (size_t)(1 * H_ + h0 + 1) * W_ + w0);
    const float4* p2t = reinterpret_cast<const float4*>(bp + (size_t)(2 * H_ + h0    ) * W_ + w0);
    const float4* p2b = reinterpret_cast<const float4*>(bp + (size_t)(2 * H_ + h0 + 1) * W_ + w0);

    const float4 a0q0 = p0t[0], a0q1 = p0t[1];
    const float4 b0q0 = p0b[0], b0q1 = p0b[1];
    const float4 a1q0 = p1t[0], a1q1 = p1t[1];
    const float4 b1q0 = p1b[0], b1q1 = p1b[1];
    const float4 a2q0 = p2t[0], a2q1 = p2t[1];
    const float4 b2q0 = p2b[0], b2q1 = p2b[1];

    // gray, top row (8 px) and bottom row (8 px)
    const float gt0 = fmaf(wb, a0q0.x, fmaf(wg, a1q0.x, wr * a2q0.x));
    const float gt1 = fmaf(wb, a0q0.y, fmaf(wg, a1q0.y, wr * a2q0.y));
    const float gt2 = fmaf(wb, a0q0.z, fmaf(wg, a1q0.z, wr * a2q0.z));
    const float gt3 = fmaf(wb, a0q0.w, fmaf(wg, a1q0.w, wr * a2q0.w));
    const float gt4 = fmaf(wb, a0q1.x, fmaf(wg, a1q1.x, wr * a2q1.x));
    const float gt5 = fmaf(wb, a0q1.y, fmaf(wg, a1q1.y, wr * a2q1.y));
    const float gt6 = fmaf(wb, a0q1.z, fmaf(wg, a1q1.z, wr * a2q1.z));
    const float gt7 = fmaf(wb, a0q1.w, fmaf(wg, a1q1.w, wr * a2q1.w));
    const float gb0 = fmaf(wb, b0q0.x, fmaf(wg, b1q0.x, wr * b2q0.x));
    const float gb1 = fmaf(wb, b0q0.y, fmaf(wg, b1q0.y, wr * b2q0.y));
    const float gb2 = fmaf(wb, b0q0.z, fmaf(wg, b1q0.z, wr * b2q0.z));
    const float gb3 = fmaf(wb, b0q0.w, fmaf(wg, b1q0.w, wr * b2q0.w));
    const float gb4 = fmaf(wb, b0q1.x, fmaf(wg, b1q1.x, wr * b2q1.x));
    const float gb5 = fmaf(wb, b0q1.y, fmaf(wg, b1q1.y, wr * b2q1.y));
    const float gb6 = fmaf(wb, b0q1.z, fmaf(wg, b1q1.z, wr * b2q1.z));
    const float gb7 = fmaf(wb, b0q1.w, fmaf(wg, b1q1.w, wr * b2q1.w));

    // Haar butterfly, four 2x2 blocks -> one float4 per output plane
    float4 vA, vH, vV, vD;
    {
        const float s_ab = gt0 + gt1, d_ab = gt0 - gt1;
        const float s_cd = gb0 + gb1, d_cd = gb0 - gb1;
        vA.x = (s_ab + s_cd) * 0.5f;  vH.x = (s_ab - s_cd) * 0.5f;
        vV.x = (d_ab + d_cd) * 0.5f;  vD.x = (d_ab - d_cd) * 0.5f;
    }
    {
        const float s_ab = gt2 + gt3, d_ab = gt2 - gt3;
        const float s_cd = gb2 + gb3, d_cd = gb2 - gb3;
        vA.y = (s_ab + s_cd) * 0.5f;  vH.y = (s_ab - s_cd) * 0.5f;
        vV.y = (d_ab + d_cd) * 0.5f;  vD.y = (d_ab - d_cd) * 0.5f;
    }
    {
        const float s_ab = gt4 + gt5, d_ab = gt4 - gt5;
        const float s_cd = gb4 + gb5, d_cd = gb4 - gb5;
        vA.z = (s_ab + s_cd) * 0.5f;  vH.z = (s_ab - s_cd) * 0.5f;
        vV.z = (d_ab + d_cd) * 0.5f;  vD.z = (d_ab - d_cd) * 0.5f;
    }
    {
        const float s_ab = gt6 + gt7, d_ab = gt6 - gt7;
        const float s_cd = gb6 + gb7, d_cd = gb6 - gb7;
        vA.w = (s_ab + s_cd) * 0.5f;  vH.w = (s_ab - s_cd) * 0.5f;
        vV.w = (d_ab + d_cd) * 0.5f;  vD.w = (d_ab - d_cd) * 0.5f;
    }

    // output: (b, k, i, j0..j0+3), plane stride OH_*OW_ ; 4 x 16B coalesced stores
    float* op = out + ((size_t)b * 4) * OH_ * OW_ + (size_t)i * OW_ + j0;
    *reinterpret_cast<float4*>(op + 0 * (size_t)OH_ * OW_) = vA;
    *reinterpret_cast<float4*>(op + 1 * (size_t)OH_ * OW_) = vH;
    *reinterpret_cast<float4*>(op + 2 * (size_t)OH_ * OW_) = vV;
    *reinterpret_cast<float4*>(op + 3 * (size_t)OH_ * OW_) = vD;
}

extern "C" void kernel_launch(void* const* d_in, const int* in_sizes, int n_in,
                              void* d_out, int out_size, void* d_ws, size_t ws_size,
                              hipStream_t stream) {
    const float* x = (const float*)d_in[0];
    float* out = (float*)d_out;

    const int total_threads = B_ * OH_ * (OW_ / 4);  // 1,048,576
    const int block = 256;
    const int grid = total_threads / block;          // 4096
    haar_gray_kernel<<<grid, block, 0, stream>>>(x, out);
}